// Round 4
// baseline (149.696 us; speedup 1.0000x reference)
//
#include <hip/hip_runtime.h>

#define N_SUBJ 4096
#define N_STEPS 2048
#define N_DOSES 8
#define NCH 64          // chunks per subject = lanes per wave
#define CLEN 32         // steps per chunk
#define LROW 36         // LDS row stride in floats (16B-aligned, bank-balanced)

#define DT   0.24609375f          // 504/2048, exact
#define HH   0.123046875f         // dt/2
#define DT6  0.041015625f         // dt/6

__device__ __forceinline__ float softplusf(float x) {
    return fmaxf(x, 0.0f) + log1pf(expf(-fabsf(x)));
}

__device__ __forceinline__ void mm3(float* C, const float* A, const float* B) {
#pragma unroll
    for (int i = 0; i < 3; ++i)
#pragma unroll
        for (int j = 0; j < 3; ++j)
            C[3 * i + j] = A[3 * i] * B[j] + A[3 * i + 1] * B[3 + j] + A[3 * i + 2] * B[6 + j];
}

// PK-only RK4 step (linear part). Emits the 4 stage Ac values c1..c4.
#define PKSTEP(Ad, Ac, Ap, c1, c2, c3, c4)                               \
    float c1 = Ac;                                                       \
    float k1a = -Ka * Ad;                                                \
    float k1c = Ka * Ad - k10 * Ac - k12 * Ac + k21 * Ap;                \
    float k1p = k12 * Ac - k21 * Ap;                                     \
    float y2a = Ad + HH * k1a, y2c = Ac + HH * k1c, y2p = Ap + HH * k1p; \
    float k2a = -Ka * y2a;                                               \
    float k2c = Ka * y2a - k10 * y2c - k12 * y2c + k21 * y2p;            \
    float k2p = k12 * y2c - k21 * y2p;                                   \
    float y3a = Ad + HH * k2a, y3c = Ac + HH * k2c, y3p = Ap + HH * k2p; \
    float k3a = -Ka * y3a;                                               \
    float k3c = Ka * y3a - k10 * y3c - k12 * y3c + k21 * y3p;            \
    float k3p = k12 * y3c - k21 * y3p;                                   \
    float y4a = Ad + DT * k3a, y4c = Ac + DT * k3c, y4p = Ap + DT * k3p; \
    float k4a = -Ka * y4a;                                               \
    float k4c = Ka * y4a - k10 * y4c - k12 * y4c + k21 * y4p;            \
    float k4p = k12 * y4c - k21 * y4p;                                   \
    float c2 = y2c, c3 = y3c, c4 = y4c;                                  \
    Ad = Ad + DT6 * (k1a + 2.0f * k2a + 2.0f * k3a + k4a);               \
    Ac = Ac + DT6 * (k1c + 2.0f * k2c + 2.0f * k3c + k4c);               \
    Ap = Ap + DT6 * (k1p + 2.0f * k2p + 2.0f * k3p + k4p);

__global__ __launch_bounds__(256, 4) void pkpd_fused_kernel(
    const float* __restrict__ cov,       // (N,2)
    const float* __restrict__ dose_int,  // (N,)
    const float* __restrict__ Wm,        // (3,9)
    const float* __restrict__ bvec,      // (9,)
    const float* __restrict__ dose_amt,  // (N,8)
    float* __restrict__ out)             // (N, N_STEPS+1, 4)
{
    __shared__ float lds[4][NCH * LROW];   // 4 waves * 9216 floats = 36 KB
    const int w = threadIdx.x >> 6;
    const int c = threadIdx.x & 63;        // lane = chunk index
    const int subj = blockIdx.x * 4 + w;
    float* myl = lds[w];

    // ---- parameter network (redundant across lanes; tiny, cache-broadcast) ----
    const float f0 = cov[2 * subj] * 0.01f;
    const float f1 = cov[2 * subj + 1];
    const float f2 = dose_int[subj];

    float P[9];
#pragma unroll
    for (int p = 0; p < 9; ++p) {
        float z = f0 * Wm[p] + f1 * Wm[9 + p] + f2 * Wm[18 + p] + bvec[p];
        P[p] = softplusf(z) + 0.01f;
    }
    const float Ka = P[0], CL = P[1], Vc = P[2], Q = P[3], Vp = P[4];
    const float Kin = P[5], Kout = P[6], Imax = P[7], IC50 = P[8];

    const float k10 = CL / Vc, k12 = Q / Vc, k21 = Q / Vp, invVc = 1.0f / Vc;
    const float IC50p = IC50 + 1e-6f;

    // R recurrence: R' = alpha*R + beta,  beta = beta0 - sum w_i * inh_i
    const float x = DT * Kout;
    const float x2 = x * x;
    const float alpha = 1.0f - x + 0.5f * x2 - (1.0f / 6.0f) * x2 * x + (1.0f / 24.0f) * x2 * x2;
    const float a = 0.5f * x;
    const float g1 = 1.0f - 2.0f * a + 2.0f * a * a - 2.0f * a * a * a;
    const float g2 = 2.0f - 2.0f * a + 2.0f * a * a;
    const float g3 = 2.0f - 2.0f * a;
    const float s0 = DT * Kin * (1.0f / 6.0f);
    const float w1 = s0 * g1, w2 = s0 * g2, w3 = s0 * g3, w4 = s0;
    const float beta0 = w1 + w2 + w3 + w4;

    // ---- Phi = one-step RK4 map of linear PK; M = Phi^32 (wave-uniform) ----
    float Am[9] = { -DT * Ka, 0.0f, 0.0f,
                     DT * Ka, -DT * (k10 + k12), DT * k21,
                     0.0f, DT * k12, -DT * k21 };
    float T2[9], T3[9], T4[9], M[9], Tmp[9];
    mm3(T2, Am, Am); mm3(T3, T2, Am); mm3(T4, T3, Am);
#pragma unroll
    for (int e = 0; e < 9; ++e)
        M[e] = Am[e] + 0.5f * T2[e] + (1.0f / 6.0f) * T3[e] + (1.0f / 24.0f) * T4[e];
    M[0] += 1.0f; M[4] += 1.0f; M[8] += 1.0f;
#pragma unroll
    for (int sq = 0; sq < 5; ++sq) { mm3(Tmp, M, M);
#pragma unroll
        for (int e = 0; e < 9; ++e) M[e] = Tmp[e]; }

    // ---- wave-parallel chunk-start PK scan (Kogge-Stone, uniform matrix) ----
    // chunk map: y_{c+1} = M*(y_c + d_c*e1) = M*y_c + d_c*Mcol0
    const float dosec = ((c & 7) == 0) ? dose_amt[subj * N_DOSES + (c >> 3)] : 0.0f;
    float vx = M[0] * dosec, vy = M[3] * dosec, vz = M[6] * dosec;
    float Md[9];
#pragma unroll
    for (int e = 0; e < 9; ++e) Md[e] = M[e];
#pragma unroll
    for (int d = 1; d <= 32; d <<= 1) {
        float ox = __shfl_up(vx, (unsigned)d, 64);
        float oy = __shfl_up(vy, (unsigned)d, 64);
        float oz = __shfl_up(vz, (unsigned)d, 64);
        if (c >= d) {
            vx += Md[0] * ox + Md[1] * oy + Md[2] * oz;
            vy += Md[3] * ox + Md[4] * oy + Md[5] * oz;
            vz += Md[6] * ox + Md[7] * oy + Md[8] * oz;
        }
        if (d < 32) { mm3(Tmp, Md, Md);
#pragma unroll
            for (int e = 0; e < 9; ++e) Md[e] = Tmp[e]; }
    }
    float ya = __shfl_up(vx, 1u, 64);
    float yb = __shfl_up(vy, 1u, 64);
    float yc = __shfl_up(vz, 1u, 64);
    if (c == 0) { ya = 0.0f; yb = 0.0f; yc = 0.0f; }

    const float Ad0 = ya + dosec, Ac0 = yb, Ap0 = yc;

    // ---- pass 1: 32 RK4 steps, collect beta[j] in regs, chunk forcing B ----
    float beta[CLEN];
    float B = 0.0f;
    {
        float Ad = Ad0, Ac = Ac0, Ap = Ap0;
#pragma unroll
        for (int j = 0; j < CLEN; ++j) {
            PKSTEP(Ad, Ac, Ap, sc1, sc2, sc3, sc4)
            float cc1 = sc1 * invVc, cc2 = sc2 * invVc;
            float cc3 = sc3 * invVc, cc4 = sc4 * invVc;
            float inh1 = __fdividef(Imax * cc1, IC50p + cc1);
            float inh2 = __fdividef(Imax * cc2, IC50p + cc2);
            float inh3 = __fdividef(Imax * cc3, IC50p + cc3);
            float inh4 = __fdividef(Imax * cc4, IC50p + cc4);
            beta[j] = beta0 - w1 * inh1 - w2 * inh2 - w3 * inh3 - w4 * inh4;
            B = alpha * B + beta[j];
        }
    }

    // ---- wave-parallel R scan (Kogge-Stone, uniform scalar alpha^32) ----
    float a32 = alpha;
#pragma unroll
    for (int sq = 0; sq < 5; ++sq) a32 = a32 * a32;
    float I = B, sfac = a32;
#pragma unroll
    for (int d = 1; d <= 32; d <<= 1) {
        float o = __shfl_up(I, (unsigned)d, 64);
        if (c >= d) I += sfac * o;
        sfac *= sfac;
    }
    float Iprev = __shfl_up(I, 1u, 64);
    if (c == 0) Iprev = 0.0f;
    float pc = 1.0f, pm = a32;
#pragma unroll
    for (int bit = 0; bit < 6; ++bit) {
        if ((c >> bit) & 1) pc *= pm;
        pm *= pm;
    }
    float R = pc * 16.0f + Iprev;   // R at chunk start

    // ---- pass 2: re-step PK (divide-free), apply beta[], stage+coalesced drain ----
    float4* orow = (float4*)out + (size_t)subj * (N_STEPS + 1);
    if (c == 0) orow[0] = make_float4(0.0f, 0.0f, 0.0f, 16.0f);

    float Ad = Ad0, Ac = Ac0, Ap = Ap0;
#pragma unroll
    for (int g = 0; g < 4; ++g) {
#pragma unroll
        for (int jj = 0; jj < 8; ++jj) {
            PKSTEP(Ad, Ac, Ap, uc1, uc2, uc3, uc4)
            (void)uc1; (void)uc2; (void)uc3; (void)uc4;
            R = alpha * R + beta[g * 8 + jj];
            *(float4*)&myl[c * LROW + jj * 4] = make_float4(Ad, Ac, Ap, R);
        }
        __syncthreads();
#pragma unroll
        for (int it = 0; it < 8; ++it) {
            const int cc = it * 8 + (c >> 3);
            const int jj = c & 7;
            float4 v = *(float4*)&myl[cc * LROW + jj * 4];
            orow[1 + cc * CLEN + g * 8 + jj] = v;
        }
        __syncthreads();
    }
}

extern "C" void kernel_launch(void* const* d_in, const int* in_sizes, int n_in,
                              void* d_out, int out_size, void* d_ws, size_t ws_size,
                              hipStream_t stream) {
    const float* cov      = (const float*)d_in[0];
    const float* dose_int = (const float*)d_in[1];
    const float* Wm       = (const float*)d_in[2];
    const float* bvec     = (const float*)d_in[3];
    const float* dose_amt = (const float*)d_in[4];
    float* out = (float*)d_out;

    pkpd_fused_kernel<<<N_SUBJ / 4, 256, 0, stream>>>(cov, dose_int, Wm, bvec, dose_amt, out);
}

// Round 8
// 89.021 us; speedup vs baseline: 1.6816x; 1.6816x over previous
//
#include <hip/hip_runtime.h>

#define N_SUBJ 4096
#define N_STEPS 2048
#define N_DOSES 8
#define NCH 64          // chunks per subject = lanes per wave
#define CLEN 32         // steps per chunk

#define DT   0.24609375f          // 504/2048, exact
#define HH   0.123046875f         // dt/2
#define DT6  0.041015625f         // dt/6

__device__ __forceinline__ float softplusf(float x) {
    return fmaxf(x, 0.0f) + log1pf(expf(-fabsf(x)));
}

__device__ __forceinline__ void mm3(float* C, const float* A, const float* B) {
#pragma unroll
    for (int i = 0; i < 3; ++i)
#pragma unroll
        for (int j = 0; j < 3; ++j)
            C[3 * i + j] = A[3 * i] * B[j] + A[3 * i + 1] * B[3 + j] + A[3 * i + 2] * B[6 + j];
}

// PK-only RK4 step (linear part). Emits the 4 stage Ac values c1..c4.
#define PKSTEP(Ad, Ac, Ap, c1, c2, c3, c4)                               \
    float c1 = Ac;                                                       \
    float k1a = -Ka * Ad;                                                \
    float k1c = Ka * Ad - k10 * Ac - k12 * Ac + k21 * Ap;                \
    float k1p = k12 * Ac - k21 * Ap;                                     \
    float y2a = Ad + HH * k1a, y2c = Ac + HH * k1c, y2p = Ap + HH * k1p; \
    float k2a = -Ka * y2a;                                               \
    float k2c = Ka * y2a - k10 * y2c - k12 * y2c + k21 * y2p;            \
    float k2p = k12 * y2c - k21 * y2p;                                   \
    float y3a = Ad + HH * k2a, y3c = Ac + HH * k2c, y3p = Ap + HH * k2p; \
    float k3a = -Ka * y3a;                                               \
    float k3c = Ka * y3a - k10 * y3c - k12 * y3c + k21 * y3p;            \
    float k3p = k12 * y3c - k21 * y3p;                                   \
    float y4a = Ad + DT * k3a, y4c = Ac + DT * k3c, y4p = Ap + DT * k3p; \
    float k4a = -Ka * y4a;                                               \
    float k4c = Ka * y4a - k10 * y4c - k12 * y4c + k21 * y4p;            \
    float k4p = k12 * y4c - k21 * y4p;                                   \
    float c2 = y2c, c3 = y3c, c4 = y4c;                                  \
    Ad = Ad + DT6 * (k1a + 2.0f * k2a + 2.0f * k3a + k4a);               \
    Ac = Ac + DT6 * (k1c + 2.0f * k2c + 2.0f * k3c + k4c);               \
    Ap = Ap + DT6 * (k1p + 2.0f * k2p + 2.0f * k3p + k4p);

__global__ __launch_bounds__(256) void pkpd_fused_kernel(
    const float* __restrict__ cov,       // (N,2)
    const float* __restrict__ dose_int,  // (N,)
    const float* __restrict__ Wm,        // (3,9)
    const float* __restrict__ bvec,      // (9,)
    const float* __restrict__ dose_amt,  // (N,8)
    float* __restrict__ out)             // (N, N_STEPS+1, 4)
{
    const int c = threadIdx.x & 63;        // lane = chunk index
    const int subj = blockIdx.x * 4 + (threadIdx.x >> 6);

    // ---- parameter network (redundant across lanes; tiny, cache-broadcast) ----
    const float f0 = cov[2 * subj] * 0.01f;
    const float f1 = cov[2 * subj + 1];
    const float f2 = dose_int[subj];

    float P[9];
#pragma unroll
    for (int p = 0; p < 9; ++p) {
        float z = f0 * Wm[p] + f1 * Wm[9 + p] + f2 * Wm[18 + p] + bvec[p];
        P[p] = softplusf(z) + 0.01f;
    }
    const float Ka = P[0], CL = P[1], Vc = P[2], Q = P[3], Vp = P[4];
    const float Kin = P[5], Kout = P[6], Imax = P[7], IC50 = P[8];

    const float k10 = CL / Vc, k12 = Q / Vc, k21 = Q / Vp, invVc = 1.0f / Vc;
    const float IC50p = IC50 + 1e-6f;

    // R recurrence: R' = alpha*R + beta,  beta = beta0 - sum w_i * inh_i
    const float x = DT * Kout;
    const float x2 = x * x;
    const float alpha = 1.0f - x + 0.5f * x2 - (1.0f / 6.0f) * x2 * x + (1.0f / 24.0f) * x2 * x2;
    const float a = 0.5f * x;
    const float g1 = 1.0f - 2.0f * a + 2.0f * a * a - 2.0f * a * a * a;
    const float g2 = 2.0f - 2.0f * a + 2.0f * a * a;
    const float g3 = 2.0f - 2.0f * a;
    const float s0 = DT * Kin * (1.0f / 6.0f);
    const float w1 = s0 * g1, w2 = s0 * g2, w3 = s0 * g3, w4 = s0;
    const float beta0 = w1 + w2 + w3 + w4;

    // ---- Phi = one-step RK4 map of linear PK; M = Phi^32 (wave-uniform) ----
    float Am[9] = { -DT * Ka, 0.0f, 0.0f,
                     DT * Ka, -DT * (k10 + k12), DT * k21,
                     0.0f, DT * k12, -DT * k21 };
    float T2[9], T3[9], T4[9], M[9], Tmp[9];
    mm3(T2, Am, Am); mm3(T3, T2, Am); mm3(T4, T3, Am);
#pragma unroll
    for (int e = 0; e < 9; ++e)
        M[e] = Am[e] + 0.5f * T2[e] + (1.0f / 6.0f) * T3[e] + (1.0f / 24.0f) * T4[e];
    M[0] += 1.0f; M[4] += 1.0f; M[8] += 1.0f;
#pragma unroll
    for (int sq = 0; sq < 5; ++sq) { mm3(Tmp, M, M);
#pragma unroll
        for (int e = 0; e < 9; ++e) M[e] = Tmp[e]; }

    // ---- wave-parallel chunk-start PK scan (Kogge-Stone, uniform matrix) ----
    // chunk map: y_{c+1} = M*(y_c + d_c*e1) = M*y_c + d_c*Mcol0
    const float dosec = ((c & 7) == 0) ? dose_amt[subj * N_DOSES + (c >> 3)] : 0.0f;
    float vx = M[0] * dosec, vy = M[3] * dosec, vz = M[6] * dosec;
    float Md[9];
#pragma unroll
    for (int e = 0; e < 9; ++e) Md[e] = M[e];
#pragma unroll
    for (int d = 1; d <= 32; d <<= 1) {
        float ox = __shfl_up(vx, (unsigned)d, 64);
        float oy = __shfl_up(vy, (unsigned)d, 64);
        float oz = __shfl_up(vz, (unsigned)d, 64);
        if (c >= d) {
            vx += Md[0] * ox + Md[1] * oy + Md[2] * oz;
            vy += Md[3] * ox + Md[4] * oy + Md[5] * oz;
            vz += Md[6] * ox + Md[7] * oy + Md[8] * oz;
        }
        if (d < 32) { mm3(Tmp, Md, Md);
#pragma unroll
            for (int e = 0; e < 9; ++e) Md[e] = Tmp[e]; }
    }
    float ya = __shfl_up(vx, 1u, 64);
    float yb = __shfl_up(vy, 1u, 64);
    float yc = __shfl_up(vz, 1u, 64);
    if (c == 0) { ya = 0.0f; yb = 0.0f; yc = 0.0f; }

    const float Ad0 = ya + dosec, Ac0 = yb, Ap0 = yc;

    // ---- pass 1: 32 RK4 steps, collect beta[j] in regs, chunk forcing B ----
    float beta[CLEN];
    float B = 0.0f;
    {
        float Ad = Ad0, Ac = Ac0, Ap = Ap0;
#pragma unroll
        for (int j = 0; j < CLEN; ++j) {
            PKSTEP(Ad, Ac, Ap, sc1, sc2, sc3, sc4)
            float cc1 = sc1 * invVc, cc2 = sc2 * invVc;
            float cc3 = sc3 * invVc, cc4 = sc4 * invVc;
            float inh1 = __fdividef(Imax * cc1, IC50p + cc1);
            float inh2 = __fdividef(Imax * cc2, IC50p + cc2);
            float inh3 = __fdividef(Imax * cc3, IC50p + cc3);
            float inh4 = __fdividef(Imax * cc4, IC50p + cc4);
            beta[j] = beta0 - w1 * inh1 - w2 * inh2 - w3 * inh3 - w4 * inh4;
            B = alpha * B + beta[j];
        }
    }

    // ---- wave-parallel R scan (Kogge-Stone, uniform scalar alpha^32) ----
    float a32 = alpha;
#pragma unroll
    for (int sq = 0; sq < 5; ++sq) a32 = a32 * a32;
    float I = B, sfac = a32;
#pragma unroll
    for (int d = 1; d <= 32; d <<= 1) {
        float o = __shfl_up(I, (unsigned)d, 64);
        if (c >= d) I += sfac * o;
        sfac *= sfac;
    }
    float Iprev = __shfl_up(I, 1u, 64);
    if (c == 0) Iprev = 0.0f;
    float pc = 1.0f, pm = a32;
#pragma unroll
    for (int bit = 0; bit < 6; ++bit) {
        if ((c >> bit) & 1) pc *= pm;
        pm *= pm;
    }
    float R = pc * 16.0f + Iprev;   // R at chunk start

    // ---- pass 2: re-step PK, apply beta[], direct per-lane stores ----
    // Each lane writes 32 consecutive float4s (8 full 128B lines written
    // back-to-back) -> L2 merges to full-line evictions (round-1-verified).
    float4* orow = (float4*)out + (size_t)subj * (N_STEPS + 1);
    if (c == 0) orow[0] = make_float4(0.0f, 0.0f, 0.0f, 16.0f);

    float4* ochunk = orow + 1 + c * CLEN;
    float Ad = Ad0, Ac = Ac0, Ap = Ap0;
#pragma unroll
    for (int j = 0; j < CLEN; ++j) {
        PKSTEP(Ad, Ac, Ap, uc1, uc2, uc3, uc4)
        (void)uc1; (void)uc2; (void)uc3; (void)uc4;
        R = alpha * R + beta[j];
        ochunk[j] = make_float4(Ad, Ac, Ap, R);
    }
}

extern "C" void kernel_launch(void* const* d_in, const int* in_sizes, int n_in,
                              void* d_out, int out_size, void* d_ws, size_t ws_size,
                              hipStream_t stream) {
    const float* cov      = (const float*)d_in[0];
    const float* dose_int = (const float*)d_in[1];
    const float* Wm       = (const float*)d_in[2];
    const float* bvec     = (const float*)d_in[3];
    const float* dose_amt = (const float*)d_in[4];
    float* out = (float*)d_out;

    pkpd_fused_kernel<<<N_SUBJ / 4, 256, 0, stream>>>(cov, dose_int, Wm, bvec, dose_amt, out);
}

// Round 9
// 46.807 us; speedup vs baseline: 3.1981x; 1.9019x over previous
//
#include <hip/hip_runtime.h>

#define N_SUBJ 4096
#define N_STEPS 2048
#define N_DOSES 8

#define DT   0.24609375f          // 504/2048, exact
#define HH   0.123046875f         // dt/2

__device__ __forceinline__ float softplusf(float x) {
    return fmaxf(x, 0.0f) + log1pf(expf(-fabsf(x)));
}

__device__ __forceinline__ void mm3(float* C, const float* A, const float* B) {
#pragma unroll
    for (int i = 0; i < 3; ++i)
#pragma unroll
        for (int j = 0; j < 3; ++j)
            C[3 * i + j] = A[3 * i] * B[j] + A[3 * i + 1] * B[3 + j] + A[3 * i + 2] * B[6 + j];
}

// Lane c owns time steps {64k + c}. PK advanced by wave-uniform matrices;
// R via per-iteration weighted Kogge-Stone scan of beta across the wave.
__global__ __launch_bounds__(256) void pkpd_tint_kernel(
    const float* __restrict__ cov,       // (N,2)
    const float* __restrict__ dose_int,  // (N,)
    const float* __restrict__ Wm,        // (3,9)
    const float* __restrict__ bvec,      // (9,)
    const float* __restrict__ dose_amt,  // (N,8)
    float* __restrict__ out)             // (N, N_STEPS+1, 4)
{
    const int c = threadIdx.x & 63;
    const int subj = blockIdx.x * 4 + (threadIdx.x >> 6);

    // ---- parameter network ----
    const float f0 = cov[2 * subj] * 0.01f;
    const float f1 = cov[2 * subj + 1];
    const float f2 = dose_int[subj];

    float P[9];
#pragma unroll
    for (int p = 0; p < 9; ++p) {
        float z = f0 * Wm[p] + f1 * Wm[9 + p] + f2 * Wm[18 + p] + bvec[p];
        P[p] = softplusf(z) + 0.01f;
    }
    const float Ka = P[0], CL = P[1], Vc = P[2], Q_ = P[3], Vp = P[4];
    const float Kin = P[5], Kout = P[6], Imax = P[7], IC50 = P[8];

    const float k10 = CL / Vc, k12 = Q_ / Vc, k21 = Q_ / Vp, invVc = 1.0f / Vc;
    const float IC50p = IC50 + 1e-6f;

    // ---- R recurrence constants: R' = alpha*R + beta ----
    const float x = DT * Kout;
    const float x2 = x * x;
    const float alpha = 1.0f - x + 0.5f * x2 - (1.0f / 6.0f) * x2 * x + (1.0f / 24.0f) * x2 * x2;
    const float a = 0.5f * x;
    const float g1 = 1.0f - 2.0f * a + 2.0f * a * a - 2.0f * a * a * a;
    const float g2 = 2.0f - 2.0f * a + 2.0f * a * a;
    const float g3 = 2.0f - 2.0f * a;
    const float s0 = DT * Kin * (1.0f / 6.0f);
    const float w1 = s0 * g1, w2 = s0 * g2, w3 = s0 * g3, w4 = s0;
    const float beta0 = w1 + w2 + w3 + w4;

    // ---- stage matrices: S2 = I+Am/2, S3 = I+Am*S2/2, S4 = I+Am*S3 ----
    float Am[9] = { -DT * Ka, 0.0f, 0.0f,
                     DT * Ka, -DT * (k10 + k12), DT * k21,
                     0.0f, DT * k12, -DT * k21 };
    float S2[9], S3[9], S4[9], G[9], Phi[9];
#pragma unroll
    for (int e = 0; e < 9; ++e) S2[e] = 0.5f * Am[e];
    S2[0] += 1.0f; S2[4] += 1.0f; S2[8] += 1.0f;
    mm3(S3, Am, S2);
#pragma unroll
    for (int e = 0; e < 9; ++e) S3[e] = 0.5f * S3[e];
    S3[0] += 1.0f; S3[4] += 1.0f; S3[8] += 1.0f;
    mm3(S4, Am, S3);
    S4[0] += 1.0f; S4[4] += 1.0f; S4[8] += 1.0f;
#pragma unroll
    for (int e = 0; e < 9; ++e) G[e] = 2.0f * (S2[e] + S3[e]) + S4[e];
    G[0] += 1.0f; G[4] += 1.0f; G[8] += 1.0f;
    mm3(Phi, Am, G);
#pragma unroll
    for (int e = 0; e < 9; ++e) Phi[e] *= (1.0f / 6.0f);
    Phi[0] += 1.0f; Phi[4] += 1.0f; Phi[8] += 1.0f;

    // stage-Ac row vectors (row index 1 of S2,S3,S4)
    const float u20 = S2[3], u21 = S2[4], u22 = S2[5];
    const float u30 = S3[3], u31 = S3[4], u32 = S3[5];
    const float u40 = S4[3], u41 = S4[4], u42 = S4[5];

    // ---- Q = Phi^63 (wave-uniform), v = Phi^c * e1 (per-lane dose vector) ----
    float Qm[9], Pc[9], Tm[9];
#pragma unroll
    for (int e = 0; e < 9; ++e) { Qm[e] = Phi[e]; Pc[e] = Phi[e]; }
    float v0 = 1.0f, v1 = 0.0f, v2 = 0.0f;
    if (c & 1) { v0 = Phi[0]; v1 = Phi[3]; v2 = Phi[6]; }   // Phi * e1
#pragma unroll
    for (int bb = 1; bb <= 5; ++bb) {
        mm3(Tm, Pc, Pc);
#pragma unroll
        for (int e = 0; e < 9; ++e) Pc[e] = Tm[e];           // Phi^(2^bb)
        mm3(Tm, Qm, Pc);
#pragma unroll
        for (int e = 0; e < 9; ++e) Qm[e] = Tm[e];           // running product -> Phi^63
        float tv0 = Pc[0] * v0 + Pc[1] * v1 + Pc[2] * v2;
        float tv1 = Pc[3] * v0 + Pc[4] * v1 + Pc[5] * v2;
        float tv2 = Pc[6] * v0 + Pc[7] * v1 + Pc[8] * v2;
        const bool bit = (c >> bb) & 1;
        v0 = bit ? tv0 : v0; v1 = bit ? tv1 : v1; v2 = bit ? tv2 : v2;
    }

    // ---- alpha powers for scan + pca = alpha^(c+1) ----
    const float a1 = alpha, a2 = a1 * a1, a4 = a2 * a2;
    const float a8 = a4 * a4, a16 = a8 * a8, a32 = a16 * a16;
    float pca = alpha;
    pca *= (c & 1)  ? a1  : 1.0f;
    pca *= (c & 2)  ? a2  : 1.0f;
    pca *= (c & 4)  ? a4  : 1.0f;
    pca *= (c & 8)  ? a8  : 1.0f;
    pca *= (c & 16) ? a16 : 1.0f;
    pca *= (c & 32) ? a32 : 1.0f;

    // ---- doses ----
    const float4 dlo = ((const float4*)(dose_amt + subj * N_DOSES))[0];
    const float4 dhi = ((const float4*)(dose_amt + subj * N_DOSES))[1];
    float ds[8] = { dlo.x, dlo.y, dlo.z, dlo.w, dhi.x, dhi.y, dhi.z, dhi.w };

    // ---- initial state: x = s_{c} (+dose at t=0 folded in) = dose0 * Phi^c e1 ----
    float x0 = ds[0] * v0, x1 = ds[0] * v1, x2v = ds[0] * v2;
    float Rcarry = 16.0f;

    float4* orow = (float4*)out + (size_t)subj * (N_STEPS + 1);
    if (c == 0) orow[0] = make_float4(0.0f, 0.0f, 0.0f, 16.0f);

#pragma unroll
    for (int k = 0; k < 32; ++k) {
        // one RK4 step at t = 64k + c:  output state = Phi * x
        float xn0 = Phi[0] * x0 + Phi[1] * x1 + Phi[2] * x2v;
        float xn1 = Phi[3] * x0 + Phi[4] * x1 + Phi[5] * x2v;
        float xn2 = Phi[6] * x0 + Phi[7] * x1 + Phi[8] * x2v;

        // stage Ac values -> beta
        float sc1 = x1;
        float sc2 = u20 * x0 + u21 * x1 + u22 * x2v;
        float sc3 = u30 * x0 + u31 * x1 + u32 * x2v;
        float sc4 = u40 * x0 + u41 * x1 + u42 * x2v;
        float cc1 = sc1 * invVc, cc2 = sc2 * invVc;
        float cc3 = sc3 * invVc, cc4 = sc4 * invVc;
        float inh1 = __fdividef(Imax * cc1, IC50p + cc1);
        float inh2 = __fdividef(Imax * cc2, IC50p + cc2);
        float inh3 = __fdividef(Imax * cc3, IC50p + cc3);
        float inh4 = __fdividef(Imax * cc4, IC50p + cc4);
        float bta = beta0 - w1 * inh1 - w2 * inh2 - w3 * inh3 - w4 * inh4;

        // weighted prefix scan: I_c = sum_{j<=c} alpha^(c-j) * beta_j
        float I = bta, o;
        o = __shfl_up(I, 1u, 64);  if (c >= 1)  I += a1  * o;
        o = __shfl_up(I, 2u, 64);  if (c >= 2)  I += a2  * o;
        o = __shfl_up(I, 4u, 64);  if (c >= 4)  I += a4  * o;
        o = __shfl_up(I, 8u, 64);  if (c >= 8)  I += a8  * o;
        o = __shfl_up(I, 16u, 64); if (c >= 16) I += a16 * o;
        o = __shfl_up(I, 32u, 64); if (c >= 32) I += a32 * o;
        float Rout = pca * Rcarry + I;

        // wave-contiguous 1KiB store: indices 64k+1 .. 64k+64
        orow[1 + k * 64 + c] = make_float4(xn0, xn1, xn2, Rout);

        Rcarry = __shfl(Rout, 63, 64);   // R_{64(k+1)}

        if (k < 31) {
            // advance 63 more steps: x <- Phi^63 * xn  (+ dose crossing at k%4==3)
            float nx0 = Qm[0] * xn0 + Qm[1] * xn1 + Qm[2] * xn2;
            float nx1 = Qm[3] * xn0 + Qm[4] * xn1 + Qm[5] * xn2;
            float nx2 = Qm[6] * xn0 + Qm[7] * xn1 + Qm[8] * xn2;
            if ((k & 3) == 3) {
                float dd = ds[(k >> 2) + 1];
                nx0 += dd * v0; nx1 += dd * v1; nx2 += dd * v2;
            }
            x0 = nx0; x1 = nx1; x2v = nx2;
        }
    }
}

extern "C" void kernel_launch(void* const* d_in, const int* in_sizes, int n_in,
                              void* d_out, int out_size, void* d_ws, size_t ws_size,
                              hipStream_t stream) {
    const float* cov      = (const float*)d_in[0];
    const float* dose_int = (const float*)d_in[1];
    const float* Wm       = (const float*)d_in[2];
    const float* bvec     = (const float*)d_in[3];
    const float* dose_amt = (const float*)d_in[4];
    float* out = (float*)d_out;

    pkpd_tint_kernel<<<N_SUBJ / 4, 256, 0, stream>>>(cov, dose_int, Wm, bvec, dose_amt, out);
}

// Round 11
// 44.109 us; speedup vs baseline: 3.3938x; 1.0612x over previous
//
#include <hip/hip_runtime.h>

#define N_SUBJ 4096
#define N_STEPS 2048
#define N_DOSES 8

#define DT   0.24609375f          // 504/2048, exact

__device__ __forceinline__ float softplusf(float x) {
    return fmaxf(x, 0.0f) + log1pf(expf(-fabsf(x)));
}

__device__ __forceinline__ void mm3(float* C, const float* A, const float* B) {
#pragma unroll
    for (int i = 0; i < 3; ++i)
#pragma unroll
        for (int j = 0; j < 3; ++j)
            C[3 * i + j] = A[3 * i] * B[j] + A[3 * i + 1] * B[3 + j] + A[3 * i + 2] * B[6 + j];
}

__device__ __forceinline__ float bperm(int addr, float v) {
    return __int_as_float(__builtin_amdgcn_ds_bpermute(addr, __float_as_int(v)));
}

// Lane c owns time steps {64k + c}. PK advanced by wave-uniform Phi / Phi^64;
// R via per-iteration weighted Kogge-Stone scan (precomputed bpermute addrs)
// with a readlane carry.
__global__ __launch_bounds__(256, 4) void pkpd_tint_kernel(
    const float* __restrict__ cov,       // (N,2)
    const float* __restrict__ dose_int,  // (N,)
    const float* __restrict__ Wm,        // (3,9)
    const float* __restrict__ bvec,      // (9,)
    const float* __restrict__ dose_amt,  // (N,8)
    float* __restrict__ out)             // (N, N_STEPS+1, 4)
{
    const int c = threadIdx.x & 63;
    const int subj = blockIdx.x * 4 + (threadIdx.x >> 6);

    // ---- parameter network ----
    const float f0 = cov[2 * subj] * 0.01f;
    const float f1 = cov[2 * subj + 1];
    const float f2 = dose_int[subj];

    float P[9];
#pragma unroll
    for (int p = 0; p < 9; ++p) {
        float z = f0 * Wm[p] + f1 * Wm[9 + p] + f2 * Wm[18 + p] + bvec[p];
        P[p] = softplusf(z) + 0.01f;
    }
    const float Ka = P[0], CL = P[1], Vc = P[2], Q_ = P[3], Vp = P[4];
    const float Kin = P[5], Kout = P[6], Imax = P[7], IC50 = P[8];

    const float k10 = CL / Vc, k12 = Q_ / Vc, k21 = Q_ / Vp, invVc = 1.0f / Vc;
    const float IC50p = IC50 + 1e-6f;

    // ---- R recurrence constants: R' = alpha*R + beta ----
    const float x = DT * Kout;
    const float x2 = x * x;
    const float alpha = 1.0f - x + 0.5f * x2 - (1.0f / 6.0f) * x2 * x + (1.0f / 24.0f) * x2 * x2;
    const float a = 0.5f * x;
    const float g1 = 1.0f - 2.0f * a + 2.0f * a * a - 2.0f * a * a * a;
    const float g2 = 2.0f - 2.0f * a + 2.0f * a * a;
    const float g3 = 2.0f - 2.0f * a;
    const float s0 = DT * Kin * (1.0f / 6.0f);
    const float w1 = s0 * g1, w2 = s0 * g2, w3 = s0 * g3, w4 = s0;
    const float beta0 = w1 + w2 + w3 + w4;

    // ---- stage matrices: S2 = I+Am/2, S3 = I+Am*S2/2, S4 = I+Am*S3 ----
    float Am[9] = { -DT * Ka, 0.0f, 0.0f,
                     DT * Ka, -DT * (k10 + k12), DT * k21,
                     0.0f, DT * k12, -DT * k21 };
    float S2[9], S3[9], S4[9], G[9], Phi[9];
#pragma unroll
    for (int e = 0; e < 9; ++e) S2[e] = 0.5f * Am[e];
    S2[0] += 1.0f; S2[4] += 1.0f; S2[8] += 1.0f;
    mm3(S3, Am, S2);
#pragma unroll
    for (int e = 0; e < 9; ++e) S3[e] = 0.5f * S3[e];
    S3[0] += 1.0f; S3[4] += 1.0f; S3[8] += 1.0f;
    mm3(S4, Am, S3);
    S4[0] += 1.0f; S4[4] += 1.0f; S4[8] += 1.0f;
#pragma unroll
    for (int e = 0; e < 9; ++e) G[e] = 2.0f * (S2[e] + S3[e]) + S4[e];
    G[0] += 1.0f; G[4] += 1.0f; G[8] += 1.0f;
    mm3(Phi, Am, G);
#pragma unroll
    for (int e = 0; e < 9; ++e) Phi[e] *= (1.0f / 6.0f);
    Phi[0] += 1.0f; Phi[4] += 1.0f; Phi[8] += 1.0f;

    // stage-Ac row vectors (row index 1 of S2,S3,S4)
    const float u20 = S2[3], u21 = S2[4], u22 = S2[5];
    const float u30 = S3[3], u31 = S3[4], u32 = S3[5];
    const float u40 = S4[3], u41 = S4[4], u42 = S4[5];

    // ---- v = Phi^c * e1 (per-lane) and F64 = Phi^64 (wave-uniform) ----
    float Pc[9], Tm[9], F64[9];
#pragma unroll
    for (int e = 0; e < 9; ++e) Pc[e] = Phi[e];
    float v0 = 1.0f, v1 = 0.0f, v2 = 0.0f;
    if (c & 1) { v0 = Pc[0]; v1 = Pc[3]; v2 = Pc[6]; }
#pragma unroll
    for (int bb = 1; bb <= 5; ++bb) {
        mm3(Tm, Pc, Pc);
#pragma unroll
        for (int e = 0; e < 9; ++e) Pc[e] = Tm[e];           // Phi^(2^bb)
        float tv0 = Pc[0] * v0 + Pc[1] * v1 + Pc[2] * v2;
        float tv1 = Pc[3] * v0 + Pc[4] * v1 + Pc[5] * v2;
        float tv2 = Pc[6] * v0 + Pc[7] * v1 + Pc[8] * v2;
        const bool bit = (c >> bb) & 1;
        v0 = bit ? tv0 : v0; v1 = bit ? tv1 : v1; v2 = bit ? tv2 : v2;
    }
    mm3(Tm, Pc, Pc);                                         // Phi^64
#pragma unroll
    for (int e = 0; e < 9; ++e) F64[e] = Tm[e];

    // ---- alpha powers for scan + pca = alpha^(c+1) ----
    const float a1 = alpha, a2 = a1 * a1, a4 = a2 * a2;
    const float a8 = a4 * a4, a16 = a8 * a8, a32 = a16 * a16;
    float pca = alpha;
    pca *= (c & 1)  ? a1  : 1.0f;
    pca *= (c & 2)  ? a2  : 1.0f;
    pca *= (c & 4)  ? a4  : 1.0f;
    pca *= (c & 8)  ? a8  : 1.0f;
    pca *= (c & 16) ? a16 : 1.0f;
    pca *= (c & 32) ? a32 : 1.0f;

    // ---- precomputed bpermute byte addresses (wrap is masked by c>=d) ----
    const int lb = c * 4;
    const int ad1 = lb - 4,  ad2 = lb - 8,   ad4 = lb - 16;
    const int ad8 = lb - 32, ad16 = lb - 64, ad32 = lb - 128;

    // ---- initial state: x = dose0 * Phi^c e1;  R carry = 16 ----
    const float dose0 = dose_amt[subj * N_DOSES + 0];
    float x0 = dose0 * v0, x1d = dose0 * v1, x2d = dose0 * v2;
    float Rc = 16.0f;
    float dnext = dose_amt[subj * N_DOSES + 1];

    float4* orow = (float4*)out + (size_t)subj * (N_STEPS + 1);
    if (c == 0) orow[0] = make_float4(0.0f, 0.0f, 0.0f, 16.0f);
    float4* op = orow + 1 + c;

#pragma unroll
    for (int seg = 0; seg < 8; ++seg) {
#pragma unroll
        for (int j = 0; j < 4; ++j) {
            const int k = seg * 4 + j;

            // output state at t = 64k+c:  xn = Phi * x
            float xn0 = Phi[0] * x0 + Phi[1] * x1d + Phi[2] * x2d;
            float xn1 = Phi[3] * x0 + Phi[4] * x1d + Phi[5] * x2d;
            float xn2 = Phi[6] * x0 + Phi[7] * x1d + Phi[8] * x2d;

            // stage Ac values -> beta
            float sc2 = u20 * x0 + u21 * x1d + u22 * x2d;
            float sc3 = u30 * x0 + u31 * x1d + u32 * x2d;
            float sc4 = u40 * x0 + u41 * x1d + u42 * x2d;
            float cc1 = x1d * invVc, cc2 = sc2 * invVc;
            float cc3 = sc3 * invVc, cc4 = sc4 * invVc;
            float inh1 = __fdividef(Imax * cc1, IC50p + cc1);
            float inh2 = __fdividef(Imax * cc2, IC50p + cc2);
            float inh3 = __fdividef(Imax * cc3, IC50p + cc3);
            float inh4 = __fdividef(Imax * cc4, IC50p + cc4);
            float bta = beta0 - w1 * inh1 - w2 * inh2 - w3 * inh3 - w4 * inh4;

            // weighted prefix scan: I_c = sum_{j<=c} alpha^(c-j) beta_j
            float I = bta, o;
            o = bperm(ad1, I);  if (c >= 1)  I = fmaf(a1,  o, I);
            o = bperm(ad2, I);  if (c >= 2)  I = fmaf(a2,  o, I);
            o = bperm(ad4, I);  if (c >= 4)  I = fmaf(a4,  o, I);
            o = bperm(ad8, I);  if (c >= 8)  I = fmaf(a8,  o, I);
            o = bperm(ad16, I); if (c >= 16) I = fmaf(a16, o, I);
            o = bperm(ad32, I); if (c >= 32) I = fmaf(a32, o, I);
            float Rout = fmaf(pca, Rc, I);

            op[k * 64] = make_float4(xn0, xn1, xn2, Rout);

            // carry R_{64(k+1)} to all lanes (SGPR broadcast)
            Rc = __int_as_float(__builtin_amdgcn_readlane(__float_as_int(Rout), 63));

            if (k < 31) {
                // advance: x <- Phi^64 * x  (+ dose at segment boundary)
                float nx0 = F64[0] * x0 + F64[1] * x1d + F64[2] * x2d;
                float nx1 = F64[3] * x0 + F64[4] * x1d + F64[5] * x2d;
                float nx2 = F64[6] * x0 + F64[7] * x1d + F64[8] * x2d;
                if (j == 3) {
                    nx0 = fmaf(dnext, v0, nx0);
                    nx1 = fmaf(dnext, v1, nx1);
                    nx2 = fmaf(dnext, v2, nx2);
                }
                x0 = nx0; x1d = nx1; x2d = nx2;
            }
        }
        if (seg < 6) dnext = dose_amt[subj * N_DOSES + seg + 2];
    }
}

extern "C" void kernel_launch(void* const* d_in, const int* in_sizes, int n_in,
                              void* d_out, int out_size, void* d_ws, size_t ws_size,
                              hipStream_t stream) {
    const float* cov      = (const float*)d_in[0];
    const float* dose_int = (const float*)d_in[1];
    const float* Wm       = (const float*)d_in[2];
    const float* bvec     = (const float*)d_in[3];
    const float* dose_amt = (const float*)d_in[4];
    float* out = (float*)d_out;

    pkpd_tint_kernel<<<N_SUBJ / 4, 256, 0, stream>>>(cov, dose_int, Wm, bvec, dose_amt, out);
}

// Round 13
// 41.818 us; speedup vs baseline: 3.5797x; 1.0548x over previous
//
#include <hip/hip_runtime.h>

#define N_SUBJ 4096
#define N_STEPS 2048
#define N_DOSES 8

#define DT   0.24609375f          // 504/2048, exact

__device__ __forceinline__ float softplusf(float x) {
    return fmaxf(x, 0.0f) + log1pf(expf(-fabsf(x)));
}

__device__ __forceinline__ void mm3(float* C, const float* A, const float* B) {
#pragma unroll
    for (int i = 0; i < 3; ++i)
#pragma unroll
        for (int j = 0; j < 3; ++j)
            C[3 * i + j] = A[3 * i] * B[j] + A[3 * i + 1] * B[3 + j] + A[3 * i + 2] * B[6 + j];
}

// DPP helper: shifted/broadcast value; lanes excluded by row_mask (or with an
// invalid source, via bound_ctrl) return 0 -> their fmaf contribution is zero.
#define DPPF(v, ctrl, rmask) __int_as_float(__builtin_amdgcn_update_dpp( \
        0, __float_as_int(v), (ctrl), (rmask), 0xf, true))

// Lane c owns time steps {64k + c}. PK advanced by wave-uniform Phi / Phi^64;
// R via per-iteration weighted DPP scan (no LDS ops) with a readlane carry.
__global__ __launch_bounds__(256, 4) void pkpd_tint_kernel(
    const float* __restrict__ cov,       // (N,2)
    const float* __restrict__ dose_int,  // (N,)
    const float* __restrict__ Wm,        // (3,9)
    const float* __restrict__ bvec,      // (9,)
    const float* __restrict__ dose_amt,  // (N,8)
    float* __restrict__ out)             // (N, N_STEPS+1, 4)
{
    const int c = threadIdx.x & 63;
    const int subj = blockIdx.x * 4 + (threadIdx.x >> 6);

    // ---- parameter network ----
    const float f0 = cov[2 * subj] * 0.01f;
    const float f1 = cov[2 * subj + 1];
    const float f2 = dose_int[subj];

    float P[9];
#pragma unroll
    for (int p = 0; p < 9; ++p) {
        float z = f0 * Wm[p] + f1 * Wm[9 + p] + f2 * Wm[18 + p] + bvec[p];
        P[p] = softplusf(z) + 0.01f;
    }
    const float Ka = P[0], CL = P[1], Vc = P[2], Q_ = P[3], Vp = P[4];
    const float Kin = P[5], Kout = P[6], Imax = P[7], IC50 = P[8];

    const float k10 = CL / Vc, k12 = Q_ / Vc, k21 = Q_ / Vp, invVc = 1.0f / Vc;
    const float IC50p = IC50 + 1e-6f;

    // ---- R recurrence constants: R' = alpha*R + beta ----
    const float x = DT * Kout;
    const float x2 = x * x;
    const float alpha = 1.0f - x + 0.5f * x2 - (1.0f / 6.0f) * x2 * x + (1.0f / 24.0f) * x2 * x2;
    const float a = 0.5f * x;
    const float g1 = 1.0f - 2.0f * a + 2.0f * a * a - 2.0f * a * a * a;
    const float g2 = 2.0f - 2.0f * a + 2.0f * a * a;
    const float g3 = 2.0f - 2.0f * a;
    const float s0 = DT * Kin * (1.0f / 6.0f);
    const float w1 = s0 * g1, w2 = s0 * g2, w3 = s0 * g3, w4 = s0;
    const float beta0 = w1 + w2 + w3 + w4;

    // ---- stage matrices: S2 = I+Am/2, S3 = I+Am*S2/2, S4 = I+Am*S3 ----
    float Am[9] = { -DT * Ka, 0.0f, 0.0f,
                     DT * Ka, -DT * (k10 + k12), DT * k21,
                     0.0f, DT * k12, -DT * k21 };
    float S2[9], S3[9], S4[9], G[9], Phi[9];
#pragma unroll
    for (int e = 0; e < 9; ++e) S2[e] = 0.5f * Am[e];
    S2[0] += 1.0f; S2[4] += 1.0f; S2[8] += 1.0f;
    mm3(S3, Am, S2);
#pragma unroll
    for (int e = 0; e < 9; ++e) S3[e] = 0.5f * S3[e];
    S3[0] += 1.0f; S3[4] += 1.0f; S3[8] += 1.0f;
    mm3(S4, Am, S3);
    S4[0] += 1.0f; S4[4] += 1.0f; S4[8] += 1.0f;
#pragma unroll
    for (int e = 0; e < 9; ++e) G[e] = 2.0f * (S2[e] + S3[e]) + S4[e];
    G[0] += 1.0f; G[4] += 1.0f; G[8] += 1.0f;
    mm3(Phi, Am, G);
#pragma unroll
    for (int e = 0; e < 9; ++e) Phi[e] *= (1.0f / 6.0f);
    Phi[0] += 1.0f; Phi[4] += 1.0f; Phi[8] += 1.0f;

    // stage-Ac row vectors (row index 1 of S2,S3,S4)
    const float u20 = S2[3], u21 = S2[4], u22 = S2[5];
    const float u30 = S3[3], u31 = S3[4], u32 = S3[5];
    const float u40 = S4[3], u41 = S4[4], u42 = S4[5];

    // ---- v = Phi^c * e1 (per-lane) and F64 = Phi^64 (wave-uniform) ----
    float Pc[9], Tm[9], F64[9];
#pragma unroll
    for (int e = 0; e < 9; ++e) Pc[e] = Phi[e];
    float v0 = 1.0f, v1 = 0.0f, v2 = 0.0f;
    if (c & 1) { v0 = Pc[0]; v1 = Pc[3]; v2 = Pc[6]; }
#pragma unroll
    for (int bb = 1; bb <= 5; ++bb) {
        mm3(Tm, Pc, Pc);
#pragma unroll
        for (int e = 0; e < 9; ++e) Pc[e] = Tm[e];           // Phi^(2^bb)
        float tv0 = Pc[0] * v0 + Pc[1] * v1 + Pc[2] * v2;
        float tv1 = Pc[3] * v0 + Pc[4] * v1 + Pc[5] * v2;
        float tv2 = Pc[6] * v0 + Pc[7] * v1 + Pc[8] * v2;
        const bool bit = (c >> bb) & 1;
        v0 = bit ? tv0 : v0; v1 = bit ? tv1 : v1; v2 = bit ? tv2 : v2;
    }
    mm3(Tm, Pc, Pc);                                         // Phi^64
#pragma unroll
    for (int e = 0; e < 9; ++e) F64[e] = Tm[e];

    // ---- alpha powers: uniform scan weights + per-lane bridge weights ----
    const float a1 = alpha, a2 = a1 * a1, a4 = a2 * a2;
    const float a8 = a4 * a4, a16 = a8 * a8, a32 = a16 * a16;
    // pca = alpha^(c+1)
    float pca = alpha;
    pca *= (c & 1)  ? a1  : 1.0f;
    pca *= (c & 2)  ? a2  : 1.0f;
    pca *= (c & 4)  ? a4  : 1.0f;
    pca *= (c & 8)  ? a8  : 1.0f;
    pca *= (c & 16) ? a16 : 1.0f;
    pca *= (c & 32) ? a32 : 1.0f;
    // w5 = alpha^((c&15)+1)  (row_bcast15 bridge, rows 1&3)
    float w5 = alpha;
    w5 *= (c & 1) ? a1 : 1.0f;
    w5 *= (c & 2) ? a2 : 1.0f;
    w5 *= (c & 4) ? a4 : 1.0f;
    w5 *= (c & 8) ? a8 : 1.0f;
    // w6 = alpha^((c&31)+1)  (row_bcast31 bridge, rows 2&3)
    float w6 = w5 * ((c & 16) ? a16 : 1.0f);

    // ---- initial state: x = dose0 * Phi^c e1;  R carry = 16 ----
    const float dose0 = dose_amt[subj * N_DOSES + 0];
    float x0 = dose0 * v0, x1d = dose0 * v1, x2d = dose0 * v2;
    float Rc = 16.0f;
    float dnext = dose_amt[subj * N_DOSES + 1];

    float4* orow = (float4*)out + (size_t)subj * (N_STEPS + 1);
    if (c == 0) orow[0] = make_float4(0.0f, 0.0f, 0.0f, 16.0f);
    float4* op = orow + 1 + c;

#pragma unroll
    for (int seg = 0; seg < 8; ++seg) {
#pragma unroll
        for (int j = 0; j < 4; ++j) {
            const int k = seg * 4 + j;

            // output state at t = 64k+c:  xn = Phi * x
            float xn0 = Phi[0] * x0 + Phi[1] * x1d + Phi[2] * x2d;
            float xn1 = Phi[3] * x0 + Phi[4] * x1d + Phi[5] * x2d;
            float xn2 = Phi[6] * x0 + Phi[7] * x1d + Phi[8] * x2d;

            // stage Ac values -> beta
            float sc2 = u20 * x0 + u21 * x1d + u22 * x2d;
            float sc3 = u30 * x0 + u31 * x1d + u32 * x2d;
            float sc4 = u40 * x0 + u41 * x1d + u42 * x2d;
            float cc1 = x1d * invVc, cc2 = sc2 * invVc;
            float cc3 = sc3 * invVc, cc4 = sc4 * invVc;
            float inh1 = __fdividef(Imax * cc1, IC50p + cc1);
            float inh2 = __fdividef(Imax * cc2, IC50p + cc2);
            float inh3 = __fdividef(Imax * cc3, IC50p + cc3);
            float inh4 = __fdividef(Imax * cc4, IC50p + cc4);
            float bta = beta0 - w1 * inh1 - w2 * inh2 - w3 * inh3 - w4 * inh4;

            // weighted inclusive scan across the wave, pure DPP (no LDS):
            // 4 row-local steps (all rows) + 2 bridge broadcasts (masked rows)
            float I = bta;
            I = fmaf(a1, DPPF(I, 0x111, 0xf), I);   // row_shr:1
            I = fmaf(a2, DPPF(I, 0x112, 0xf), I);   // row_shr:2
            I = fmaf(a4, DPPF(I, 0x114, 0xf), I);   // row_shr:4
            I = fmaf(a8, DPPF(I, 0x118, 0xf), I);   // row_shr:8
            I = fmaf(w5, DPPF(I, 0x142, 0xa), I);   // row_bcast:15 -> rows 1,3
            I = fmaf(w6, DPPF(I, 0x143, 0xc), I);   // row_bcast:31 -> rows 2,3
            float Rout = fmaf(pca, Rc, I);

            op[k * 64] = make_float4(xn0, xn1, xn2, Rout);

            // carry R_{64(k+1)} to all lanes (SGPR broadcast)
            Rc = __int_as_float(__builtin_amdgcn_readlane(__float_as_int(Rout), 63));

            if (k < 31) {
                // advance: x <- Phi^64 * x  (+ dose at segment boundary)
                float nx0 = F64[0] * x0 + F64[1] * x1d + F64[2] * x2d;
                float nx1 = F64[3] * x0 + F64[4] * x1d + F64[5] * x2d;
                float nx2 = F64[6] * x0 + F64[7] * x1d + F64[8] * x2d;
                if (j == 3) {
                    nx0 = fmaf(dnext, v0, nx0);
                    nx1 = fmaf(dnext, v1, nx1);
                    nx2 = fmaf(dnext, v2, nx2);
                }
                x0 = nx0; x1d = nx1; x2d = nx2;
            }
        }
        if (seg < 6) dnext = dose_amt[subj * N_DOSES + seg + 2];
    }
}

extern "C" void kernel_launch(void* const* d_in, const int* in_sizes, int n_in,
                              void* d_out, int out_size, void* d_ws, size_t ws_size,
                              hipStream_t stream) {
    const float* cov      = (const float*)d_in[0];
    const float* dose_int = (const float*)d_in[1];
    const float* Wm       = (const float*)d_in[2];
    const float* bvec     = (const float*)d_in[3];
    const float* dose_amt = (const float*)d_in[4];
    float* out = (float*)d_out;

    pkpd_tint_kernel<<<N_SUBJ / 4, 256, 0, stream>>>(cov, dose_int, Wm, bvec, dose_amt, out);
}

// Round 14
// 37.977 us; speedup vs baseline: 3.9418x; 1.1012x over previous
//
#include <hip/hip_runtime.h>

#define N_SUBJ 4096
#define N_STEPS 2048
#define N_DOSES 8

#define DT   0.24609375f          // 504/2048, exact

__device__ __forceinline__ float softplusf(float x) {
    return fmaxf(x, 0.0f) + log1pf(expf(-fabsf(x)));
}

__device__ __forceinline__ void mm3(float* C, const float* A, const float* B) {
#pragma unroll
    for (int i = 0; i < 3; ++i)
#pragma unroll
        for (int j = 0; j < 3; ++j)
            C[3 * i + j] = A[3 * i] * B[j] + A[3 * i + 1] * B[3 + j] + A[3 * i + 2] * B[6 + j];
}

// DPP helper: shifted/broadcast value; lanes excluded by row_mask (or with an
// invalid source, via bound_ctrl) return 0 -> their fmaf contribution is zero.
#define DPPF(v, ctrl, rmask) __int_as_float(__builtin_amdgcn_update_dpp( \
        0, __float_as_int(v), (ctrl), (rmask), 0xf, true))

// wave-uniform value -> SGPR
__device__ __forceinline__ float rfl(float x) {
    return __int_as_float(__builtin_amdgcn_readfirstlane(__float_as_int(x)));
}

// Lane c owns time steps {64k + c}. PK advanced by wave-uniform Phi / Phi^64
// (held in SGPRs); R via per-iteration weighted DPP scan + readlane carry.
__global__ __launch_bounds__(256, 4) void pkpd_tint_kernel(
    const float* __restrict__ cov,       // (N,2)
    const float* __restrict__ dose_int,  // (N,)
    const float* __restrict__ Wm,        // (3,9)
    const float* __restrict__ bvec,      // (9,)
    const float* __restrict__ dose_amt,  // (N,8)
    float* __restrict__ out)             // (N, N_STEPS+1, 4)
{
    const int c = threadIdx.x & 63;
    const int subj = blockIdx.x * 4 + (threadIdx.x >> 6);

    // ---- parameter network ----
    const float f0 = cov[2 * subj] * 0.01f;
    const float f1 = cov[2 * subj + 1];
    const float f2 = dose_int[subj];

    float P[9];
#pragma unroll
    for (int p = 0; p < 9; ++p) {
        float z = f0 * Wm[p] + f1 * Wm[9 + p] + f2 * Wm[18 + p] + bvec[p];
        P[p] = softplusf(z) + 0.01f;
    }
    const float Ka = P[0], CL = P[1], Vc = P[2], Q_ = P[3], Vp = P[4];
    const float Kin = P[5], Kout = P[6], Imax = P[7], IC50 = P[8];

    const float k10 = CL / Vc, k12 = Q_ / Vc, k21 = Q_ / Vp;
    const float IC50p = IC50 + 1e-6f;

    // ---- R recurrence constants: R' = alpha*R + beta ----
    const float x = DT * Kout;
    const float x2 = x * x;
    const float alpha = 1.0f - x + 0.5f * x2 - (1.0f / 6.0f) * x2 * x + (1.0f / 24.0f) * x2 * x2;
    const float a = 0.5f * x;
    const float g1 = 1.0f - 2.0f * a + 2.0f * a * a - 2.0f * a * a * a;
    const float g2 = 2.0f - 2.0f * a + 2.0f * a * a;
    const float g3 = 2.0f - 2.0f * a;
    const float s0 = DT * Kin * (1.0f / 6.0f);
    const float w1 = s0 * g1, w2 = s0 * g2, w3 = s0 * g3, w4 = s0;
    const float beta0v = w1 + w2 + w3 + w4;

    // ---- stage matrices: S2 = I+Am/2, S3 = I+Am*S2/2, S4 = I+Am*S3 ----
    float Am[9] = { -DT * Ka, 0.0f, 0.0f,
                     DT * Ka, -DT * (k10 + k12), DT * k21,
                     0.0f, DT * k12, -DT * k21 };
    float S2[9], S3[9], S4[9], G[9], Phi[9];
#pragma unroll
    for (int e = 0; e < 9; ++e) S2[e] = 0.5f * Am[e];
    S2[0] += 1.0f; S2[4] += 1.0f; S2[8] += 1.0f;
    mm3(S3, Am, S2);
#pragma unroll
    for (int e = 0; e < 9; ++e) S3[e] = 0.5f * S3[e];
    S3[0] += 1.0f; S3[4] += 1.0f; S3[8] += 1.0f;
    mm3(S4, Am, S3);
    S4[0] += 1.0f; S4[4] += 1.0f; S4[8] += 1.0f;
#pragma unroll
    for (int e = 0; e < 9; ++e) G[e] = 2.0f * (S2[e] + S3[e]) + S4[e];
    G[0] += 1.0f; G[4] += 1.0f; G[8] += 1.0f;
    mm3(Phi, Am, G);
#pragma unroll
    for (int e = 0; e < 9; ++e) Phi[e] *= (1.0f / 6.0f);
    Phi[0] += 1.0f; Phi[4] += 1.0f; Phi[8] += 1.0f;

    // ---- v = Phi^c * e1 (per-lane) and F64 = Phi^64 (wave-uniform) ----
    float Pc[9], Tm[9], F64[9];
#pragma unroll
    for (int e = 0; e < 9; ++e) Pc[e] = Phi[e];
    float v0 = 1.0f, v1 = 0.0f, v2 = 0.0f;
    if (c & 1) { v0 = Pc[0]; v1 = Pc[3]; v2 = Pc[6]; }
#pragma unroll
    for (int bb = 1; bb <= 5; ++bb) {
        mm3(Tm, Pc, Pc);
#pragma unroll
        for (int e = 0; e < 9; ++e) Pc[e] = Tm[e];           // Phi^(2^bb)
        float tv0 = Pc[0] * v0 + Pc[1] * v1 + Pc[2] * v2;
        float tv1 = Pc[3] * v0 + Pc[4] * v1 + Pc[5] * v2;
        float tv2 = Pc[6] * v0 + Pc[7] * v1 + Pc[8] * v2;
        const bool bit = (c >> bb) & 1;
        v0 = bit ? tv0 : v0; v1 = bit ? tv1 : v1; v2 = bit ? tv2 : v2;
    }
    mm3(Tm, Pc, Pc);                                         // Phi^64

    // ---- hoist wave-uniform constants to SGPRs ----
    float sPhi[9], sF64[9], sU[9];
#pragma unroll
    for (int e = 0; e < 9; ++e) {
        sPhi[e] = rfl(Phi[e]);
        sF64[e] = rfl(Tm[e]);
    }
    sU[0] = rfl(S2[3]); sU[1] = rfl(S2[4]); sU[2] = rfl(S2[5]);
    sU[3] = rfl(S3[3]); sU[4] = rfl(S3[4]); sU[5] = rfl(S3[5]);
    sU[6] = rfl(S4[3]); sU[7] = rfl(S4[4]); sU[8] = rfl(S4[5]);
    const float sD    = rfl(IC50p * Vc);          // denom scaled by Vc
    const float sWW1  = rfl(w1 * Imax);
    const float sWW2  = rfl(w2 * Imax);
    const float sWW3  = rfl(w3 * Imax);
    const float sWW4  = rfl(w4 * Imax);
    const float sB0   = rfl(beta0v);

    // ---- alpha powers: uniform scan weights + per-lane bridge weights ----
    // (DPP/VOP2 src1 must be VGPR -> keep these as VGPR floats)
    const float a1 = alpha, a2 = a1 * a1, a4 = a2 * a2;
    const float a8 = a4 * a4, a16 = a8 * a8, a32 = a16 * a16;
    float pca = alpha;              // alpha^(c+1)
    pca *= (c & 1)  ? a1  : 1.0f;
    pca *= (c & 2)  ? a2  : 1.0f;
    pca *= (c & 4)  ? a4  : 1.0f;
    pca *= (c & 8)  ? a8  : 1.0f;
    pca *= (c & 16) ? a16 : 1.0f;
    pca *= (c & 32) ? a32 : 1.0f;
    float w5 = alpha;               // alpha^((c&15)+1), bridge rows 1&3
    w5 *= (c & 1) ? a1 : 1.0f;
    w5 *= (c & 2) ? a2 : 1.0f;
    w5 *= (c & 4) ? a4 : 1.0f;
    w5 *= (c & 8) ? a8 : 1.0f;
    float w6 = w5 * ((c & 16) ? a16 : 1.0f);   // alpha^((c&31)+1), rows 2&3

    // ---- doses (all 8 in regs; indices below are compile-time) ----
    const float4 dlo = ((const float4*)(dose_amt + subj * N_DOSES))[0];
    const float4 dhi = ((const float4*)(dose_amt + subj * N_DOSES))[1];
    const float ds[8] = { dlo.x, dlo.y, dlo.z, dlo.w, dhi.x, dhi.y, dhi.z, dhi.w };

    // ---- initial state: x = dose0 * Phi^c e1;  R carry = 16 ----
    float x0 = ds[0] * v0, x1d = ds[0] * v1, x2d = ds[0] * v2;
    float Rc = 16.0f;

    float4* orow = (float4*)out + (size_t)subj * (N_STEPS + 1);
    if (c == 0) orow[0] = make_float4(0.0f, 0.0f, 0.0f, 16.0f);
    float4* op = orow + 1 + c;

    // beta(x): paired-divide form. s_i = stage Ac values; d_i = sD + s_i;
    // beta = sB0 - (ww1*s1*d2 + ww2*s2*d1)/(d1*d2) - (ww3*s3*d4 + ww4*s4*d3)/(d3*d4)
#define BETA_FROM_X(bout)                                                  \
    do {                                                                   \
        float s1_ = x1d;                                                   \
        float s2_ = sU[0] * x0 + sU[1] * x1d + sU[2] * x2d;                \
        float s3_ = sU[3] * x0 + sU[4] * x1d + sU[5] * x2d;                \
        float s4_ = sU[6] * x0 + sU[7] * x1d + sU[8] * x2d;                \
        float d1_ = sD + s1_, d2_ = sD + s2_;                              \
        float d3_ = sD + s3_, d4_ = sD + s4_;                              \
        float n12_ = fmaf(sWW1 * s1_, d2_, (sWW2 * s2_) * d1_);            \
        float n34_ = fmaf(sWW3 * s3_, d4_, (sWW4 * s4_) * d3_);            \
        float t12_ = __fdividef(n12_, d1_ * d2_);                          \
        float t34_ = __fdividef(n34_, d3_ * d4_);                          \
        bout = sB0 - t12_ - t34_;                                          \
    } while (0)

    float bta;
    BETA_FROM_X(bta);

#pragma unroll
    for (int k = 0; k < 32; ++k) {
        // output state at t = 64k+c:  xn = Phi * x
        float xn0 = sPhi[0] * x0 + sPhi[1] * x1d + sPhi[2] * x2d;
        float xn1 = sPhi[3] * x0 + sPhi[4] * x1d + sPhi[5] * x2d;
        float xn2 = sPhi[6] * x0 + sPhi[7] * x1d + sPhi[8] * x2d;

        // weighted inclusive scan across the wave, pure DPP (no LDS):
        float I = bta;
        I = fmaf(a1, DPPF(I, 0x111, 0xf), I);   // row_shr:1
        I = fmaf(a2, DPPF(I, 0x112, 0xf), I);   // row_shr:2
        I = fmaf(a4, DPPF(I, 0x114, 0xf), I);   // row_shr:4
        I = fmaf(a8, DPPF(I, 0x118, 0xf), I);   // row_shr:8
        I = fmaf(w5, DPPF(I, 0x142, 0xa), I);   // row_bcast:15 -> rows 1,3
        I = fmaf(w6, DPPF(I, 0x143, 0xc), I);   // row_bcast:31 -> rows 2,3

        // advance + next beta (independent of the scan chain; gives the
        // scheduler work to fill the DPP-chain stalls)
        if (k < 31) {
            float nx0 = sF64[0] * x0 + sF64[1] * x1d + sF64[2] * x2d;
            float nx1 = sF64[3] * x0 + sF64[4] * x1d + sF64[5] * x2d;
            float nx2 = sF64[6] * x0 + sF64[7] * x1d + sF64[8] * x2d;
            if ((k & 3) == 3) {
                const float dd = ds[(k >> 2) + 1];
                nx0 = fmaf(dd, v0, nx0);
                nx1 = fmaf(dd, v1, nx1);
                nx2 = fmaf(dd, v2, nx2);
            }
            x0 = nx0; x1d = nx1; x2d = nx2;
            BETA_FROM_X(bta);
        }

        float Rout = fmaf(pca, Rc, I);
        op[k * 64] = make_float4(xn0, xn1, xn2, Rout);

        // carry R_{64(k+1)} to all lanes (SGPR broadcast)
        Rc = __int_as_float(__builtin_amdgcn_readlane(__float_as_int(Rout), 63));
    }
#undef BETA_FROM_X
}

extern "C" void kernel_launch(void* const* d_in, const int* in_sizes, int n_in,
                              void* d_out, int out_size, void* d_ws, size_t ws_size,
                              hipStream_t stream) {
    const float* cov      = (const float*)d_in[0];
    const float* dose_int = (const float*)d_in[1];
    const float* Wm       = (const float*)d_in[2];
    const float* bvec     = (const float*)d_in[3];
    const float* dose_amt = (const float*)d_in[4];
    float* out = (float*)d_out;

    pkpd_tint_kernel<<<N_SUBJ / 4, 256, 0, stream>>>(cov, dose_int, Wm, bvec, dose_amt, out);
}

// Round 15
// 32.650 us; speedup vs baseline: 4.5849x; 1.1632x over previous
//
#include <hip/hip_runtime.h>

#define N_SUBJ 4096
#define N_STEPS 2048
#define N_DOSES 8

#define DT   0.24609375f          // 504/2048, exact

__device__ __forceinline__ float softplusf(float x) {
    return fmaxf(x, 0.0f) + log1pf(expf(-fabsf(x)));
}

__device__ __forceinline__ void mm3(float* C, const float* A, const float* B) {
#pragma unroll
    for (int i = 0; i < 3; ++i)
#pragma unroll
        for (int j = 0; j < 3; ++j)
            C[3 * i + j] = A[3 * i] * B[j] + A[3 * i + 1] * B[3 + j] + A[3 * i + 2] * B[6 + j];
}

// DPP helper: shifted/broadcast value; lanes excluded by row_mask (or with an
// invalid source, via bound_ctrl) return 0 -> their fmaf contribution is zero.
#define DPPF(v, ctrl, rmask) __int_as_float(__builtin_amdgcn_update_dpp( \
        0, __float_as_int(v), (ctrl), (rmask), 0xf, true))

// wave-uniform value -> SGPR
__device__ __forceinline__ float rfl(float x) {
    return __int_as_float(__builtin_amdgcn_readfirstlane(__float_as_int(x)));
}

// Lane c owns time steps {64k + c}. PK advanced by wave-uniform Phi / Phi^64
// (held in SGPRs); R via per-iteration weighted DPP scan + readlane carry.
__global__ __launch_bounds__(256, 4) void pkpd_tint_kernel(
    const float* __restrict__ cov,       // (N,2)
    const float* __restrict__ dose_int,  // (N,)
    const float* __restrict__ Wm,        // (3,9)
    const float* __restrict__ bvec,      // (9,)
    const float* __restrict__ dose_amt,  // (N,8)
    float* __restrict__ out)             // (N, N_STEPS+1, 4)
{
    const int c = threadIdx.x & 63;
    const int subj = blockIdx.x * 4 + (threadIdx.x >> 6);

    // ---- parameter network ----
    const float f0 = cov[2 * subj] * 0.01f;
    const float f1 = cov[2 * subj + 1];
    const float f2 = dose_int[subj];

    float P[9];
#pragma unroll
    for (int p = 0; p < 9; ++p) {
        float z = f0 * Wm[p] + f1 * Wm[9 + p] + f2 * Wm[18 + p] + bvec[p];
        P[p] = softplusf(z) + 0.01f;
    }
    const float Ka = P[0], CL = P[1], Vc = P[2], Q_ = P[3], Vp = P[4];
    const float Kin = P[5], Kout = P[6], Imax = P[7], IC50 = P[8];

    const float k10 = CL / Vc, k12 = Q_ / Vc, k21 = Q_ / Vp;
    const float IC50p = IC50 + 1e-6f;

    // ---- R recurrence constants: R' = alpha*R + beta ----
    const float x = DT * Kout;
    const float x2 = x * x;
    const float alpha = 1.0f - x + 0.5f * x2 - (1.0f / 6.0f) * x2 * x + (1.0f / 24.0f) * x2 * x2;
    const float a = 0.5f * x;
    const float g1 = 1.0f - 2.0f * a + 2.0f * a * a - 2.0f * a * a * a;
    const float g2 = 2.0f - 2.0f * a + 2.0f * a * a;
    const float g3 = 2.0f - 2.0f * a;
    const float s0 = DT * Kin * (1.0f / 6.0f);
    const float w1 = s0 * g1, w2 = s0 * g2, w3 = s0 * g3, w4 = s0;
    const float beta0v = w1 + w2 + w3 + w4;

    // ---- stage matrices: S2 = I+Am/2, S3 = I+Am*S2/2, S4 = I+Am*S3 ----
    float Am[9] = { -DT * Ka, 0.0f, 0.0f,
                     DT * Ka, -DT * (k10 + k12), DT * k21,
                     0.0f, DT * k12, -DT * k21 };
    float S2[9], S3[9], S4[9], G[9], Phi[9];
#pragma unroll
    for (int e = 0; e < 9; ++e) S2[e] = 0.5f * Am[e];
    S2[0] += 1.0f; S2[4] += 1.0f; S2[8] += 1.0f;
    mm3(S3, Am, S2);
#pragma unroll
    for (int e = 0; e < 9; ++e) S3[e] = 0.5f * S3[e];
    S3[0] += 1.0f; S3[4] += 1.0f; S3[8] += 1.0f;
    mm3(S4, Am, S3);
    S4[0] += 1.0f; S4[4] += 1.0f; S4[8] += 1.0f;
#pragma unroll
    for (int e = 0; e < 9; ++e) G[e] = 2.0f * (S2[e] + S3[e]) + S4[e];
    G[0] += 1.0f; G[4] += 1.0f; G[8] += 1.0f;
    mm3(Phi, Am, G);
#pragma unroll
    for (int e = 0; e < 9; ++e) Phi[e] *= (1.0f / 6.0f);
    Phi[0] += 1.0f; Phi[4] += 1.0f; Phi[8] += 1.0f;

    // ---- v = Phi^c * e1 (per-lane) and F64 = Phi^64 (wave-uniform) ----
    float Pc[9], Tm[9];
#pragma unroll
    for (int e = 0; e < 9; ++e) Pc[e] = Phi[e];
    float v0 = 1.0f, v1 = 0.0f, v2 = 0.0f;
    if (c & 1) { v0 = Pc[0]; v1 = Pc[3]; v2 = Pc[6]; }
#pragma unroll
    for (int bb = 1; bb <= 5; ++bb) {
        mm3(Tm, Pc, Pc);
#pragma unroll
        for (int e = 0; e < 9; ++e) Pc[e] = Tm[e];           // Phi^(2^bb)
        float tv0 = Pc[0] * v0 + Pc[1] * v1 + Pc[2] * v2;
        float tv1 = Pc[3] * v0 + Pc[4] * v1 + Pc[5] * v2;
        float tv2 = Pc[6] * v0 + Pc[7] * v1 + Pc[8] * v2;
        const bool bit = (c >> bb) & 1;
        v0 = bit ? tv0 : v0; v1 = bit ? tv1 : v1; v2 = bit ? tv2 : v2;
    }
    mm3(Tm, Pc, Pc);                                         // Phi^64

    // ---- hoist wave-uniform constants to SGPRs ----
    float sPhi[9], sF64[9], sU[9];
#pragma unroll
    for (int e = 0; e < 9; ++e) {
        sPhi[e] = rfl(Phi[e]);
        sF64[e] = rfl(Tm[e]);
    }
    sU[0] = rfl(S2[3]); sU[1] = rfl(S2[4]); sU[2] = rfl(S2[5]);
    sU[3] = rfl(S3[3]); sU[4] = rfl(S3[4]); sU[5] = rfl(S3[5]);
    sU[6] = rfl(S4[3]); sU[7] = rfl(S4[4]); sU[8] = rfl(S4[5]);
    const float sD    = rfl(IC50p * Vc);          // denom scaled by Vc
    const float sWW1  = rfl(w1 * Imax);
    const float sWW2  = rfl(w2 * Imax);
    const float sWW3  = rfl(w3 * Imax);
    const float sWW4  = rfl(w4 * Imax);
    const float sB0   = rfl(beta0v);

    // ---- alpha powers: uniform scan weights + per-lane bridge weights ----
    // (DPP/VOP2 src1 must be VGPR -> keep these as VGPR floats)
    const float a1 = alpha, a2 = a1 * a1, a4 = a2 * a2;
    const float a8 = a4 * a4, a16 = a8 * a8, a32 = a16 * a16;
    float pca = alpha;              // alpha^(c+1)
    pca *= (c & 1)  ? a1  : 1.0f;
    pca *= (c & 2)  ? a2  : 1.0f;
    pca *= (c & 4)  ? a4  : 1.0f;
    pca *= (c & 8)  ? a8  : 1.0f;
    pca *= (c & 16) ? a16 : 1.0f;
    pca *= (c & 32) ? a32 : 1.0f;
    float w5 = alpha;               // alpha^((c&15)+1), bridge rows 1&3
    w5 *= (c & 1) ? a1 : 1.0f;
    w5 *= (c & 2) ? a2 : 1.0f;
    w5 *= (c & 4) ? a4 : 1.0f;
    w5 *= (c & 8) ? a8 : 1.0f;
    float w6 = w5 * ((c & 16) ? a16 : 1.0f);   // alpha^((c&31)+1), rows 2&3

    // ---- doses (all 8 in regs; indices below are compile-time) ----
    const float4 dlo = ((const float4*)(dose_amt + subj * N_DOSES))[0];
    const float4 dhi = ((const float4*)(dose_amt + subj * N_DOSES))[1];
    const float ds[8] = { dlo.x, dlo.y, dlo.z, dlo.w, dhi.x, dhi.y, dhi.z, dhi.w };

    // ---- initial state: x = dose0 * Phi^c e1;  R carry = 16 ----
    float x0 = ds[0] * v0, x1d = ds[0] * v1, x2d = ds[0] * v2;
    float Rc = 16.0f;

    float4* orow = (float4*)out + (size_t)subj * (N_STEPS + 1);
    if (c == 0) orow[0] = make_float4(0.0f, 0.0f, 0.0f, 16.0f);
    float4* op = orow + 1 + c;

    // beta(x): single-rcp form (no IEEE div sequence, no VCC serialization).
    // s_i = stage Ac values; d_i = sD + s_i;
    // beta = sB0 - (n12*d34 + n34*d12) * rcp(d12*d34)
    //   n12 = ww1*s1*d2 + ww2*s2*d1,  n34 = ww3*s3*d4 + ww4*s4*d3
#define BETA_FROM_X(bout)                                                  \
    do {                                                                   \
        float s1_ = x1d;                                                   \
        float s2_ = sU[0] * x0 + sU[1] * x1d + sU[2] * x2d;                \
        float s3_ = sU[3] * x0 + sU[4] * x1d + sU[5] * x2d;                \
        float s4_ = sU[6] * x0 + sU[7] * x1d + sU[8] * x2d;                \
        float d1_ = sD + s1_, d2_ = sD + s2_;                              \
        float d3_ = sD + s3_, d4_ = sD + s4_;                              \
        float n12_ = fmaf(sWW1 * s1_, d2_, (sWW2 * s2_) * d1_);            \
        float n34_ = fmaf(sWW3 * s3_, d4_, (sWW4 * s4_) * d3_);            \
        float d12_ = d1_ * d2_, d34_ = d3_ * d4_;                          \
        float num_ = fmaf(n12_, d34_, n34_ * d12_);                        \
        float rcp_ = __builtin_amdgcn_rcpf(d12_ * d34_);                   \
        bout = sB0 - num_ * rcp_;                                          \
    } while (0)

    float bta;
    BETA_FROM_X(bta);

#pragma unroll
    for (int k = 0; k < 32; ++k) {
        // output state at t = 64k+c:  xn = Phi * x
        float xn0 = sPhi[0] * x0 + sPhi[1] * x1d + sPhi[2] * x2d;
        float xn1 = sPhi[3] * x0 + sPhi[4] * x1d + sPhi[5] * x2d;
        float xn2 = sPhi[6] * x0 + sPhi[7] * x1d + sPhi[8] * x2d;

        // weighted inclusive scan across the wave, pure DPP (no LDS):
        float I = bta;
        I = fmaf(a1, DPPF(I, 0x111, 0xf), I);   // row_shr:1
        I = fmaf(a2, DPPF(I, 0x112, 0xf), I);   // row_shr:2
        I = fmaf(a4, DPPF(I, 0x114, 0xf), I);   // row_shr:4
        I = fmaf(a8, DPPF(I, 0x118, 0xf), I);   // row_shr:8
        I = fmaf(w5, DPPF(I, 0x142, 0xa), I);   // row_bcast:15 -> rows 1,3
        I = fmaf(w6, DPPF(I, 0x143, 0xc), I);   // row_bcast:31 -> rows 2,3

        // advance + next beta (independent of the scan chain; gives the
        // scheduler work to fill the DPP-chain stalls)
        if (k < 31) {
            float nx0 = sF64[0] * x0 + sF64[1] * x1d + sF64[2] * x2d;
            float nx1 = sF64[3] * x0 + sF64[4] * x1d + sF64[5] * x2d;
            float nx2 = sF64[6] * x0 + sF64[7] * x1d + sF64[8] * x2d;
            if ((k & 3) == 3) {
                const float dd = ds[(k >> 2) + 1];
                nx0 = fmaf(dd, v0, nx0);
                nx1 = fmaf(dd, v1, nx1);
                nx2 = fmaf(dd, v2, nx2);
            }
            x0 = nx0; x1d = nx1; x2d = nx2;
            BETA_FROM_X(bta);
        }

        float Rout = fmaf(pca, Rc, I);
        op[k * 64] = make_float4(xn0, xn1, xn2, Rout);

        // carry R_{64(k+1)} to all lanes (SGPR broadcast)
        Rc = __int_as_float(__builtin_amdgcn_readlane(__float_as_int(Rout), 63));
    }
#undef BETA_FROM_X
}

extern "C" void kernel_launch(void* const* d_in, const int* in_sizes, int n_in,
                              void* d_out, int out_size, void* d_ws, size_t ws_size,
                              hipStream_t stream) {
    const float* cov      = (const float*)d_in[0];
    const float* dose_int = (const float*)d_in[1];
    const float* Wm       = (const float*)d_in[2];
    const float* bvec     = (const float*)d_in[3];
    const float* dose_amt = (const float*)d_in[4];
    float* out = (float*)d_out;

    pkpd_tint_kernel<<<N_SUBJ / 4, 256, 0, stream>>>(cov, dose_int, Wm, bvec, dose_amt, out);
}